// Round 1
// baseline (318.700 us; speedup 1.0000x reference)
//
#include <hip/hip_runtime.h>
#include <hip/hip_bf16.h>

typedef unsigned short ushort_t;
typedef __attribute__((ext_vector_type(8))) short short8;
typedef __attribute__((ext_vector_type(4))) float f32x4;

#define EMBED 1024
#define NHEAD 16
#define HDIM 64
#define BB 2
#define SSEQ 2048
#define MROWS (BB*SSEQ)   // 4096

__device__ __forceinline__ ushort_t f2bf(float f) {
    union { float f; unsigned int u; } x; x.f = f;
    unsigned int r = x.u + 0x7fffu + ((x.u >> 16) & 1u);
    return (ushort_t)(r >> 16);
}

// ---------------- cast x (fp32 -> bf16), vectorized ----------------
__global__ void cast_bf16_kernel(const float* __restrict__ in, ushort_t* __restrict__ out, int n) {
    int i = (blockIdx.x * blockDim.x + threadIdx.x) * 4;
    if (i + 3 < n) {
        float4 v = *(const float4*)(in + i);
        out[i+0] = f2bf(v.x); out[i+1] = f2bf(v.y);
        out[i+2] = f2bf(v.z); out[i+3] = f2bf(v.w);
    }
}

// ---------------- W [K,N] fp32 -> Wt [N,K] bf16, tiled ----------------
__global__ void transpose_cast_kernel(const float* __restrict__ W, ushort_t* __restrict__ Wt) {
    __shared__ float tile[32][33];
    int tx = threadIdx.x, ty = threadIdx.y;   // 32 x 8
    int n0 = blockIdx.x * 32, k0 = blockIdx.y * 32;
    #pragma unroll
    for (int i = 0; i < 4; i++)
        tile[ty*4+i][tx] = W[(size_t)(k0 + ty*4 + i) * EMBED + n0 + tx];
    __syncthreads();
    #pragma unroll
    for (int i = 0; i < 4; i++)
        Wt[(size_t)(n0 + ty*4 + i) * EMBED + k0 + tx] = f2bf(tile[tx][ty*4+i]);
}

// ---------------- GEMM: C[M,N] = A[M,K] * Bt[N,K]^T + bias ----------------
// OUT_MODE 0: fp32 row-major C. OUT_MODE 1: bf16 scatter to [B,H,S,Dh] (qkv).
template<int OUT_MODE>
__global__ __launch_bounds__(256) void gemm_bt_kernel(
    const ushort_t* __restrict__ A,   // [M,K] bf16
    const ushort_t* __restrict__ Bt,  // [N,K] bf16
    const float* __restrict__ bias,   // [N]
    void* __restrict__ Cout,
    int M, int N, int K)
{
    __shared__ __attribute__((aligned(16))) ushort_t Asm[128*32];
    __shared__ __attribute__((aligned(16))) ushort_t Bsm[128*32];
    int t = threadIdx.x;
    int w = t >> 6, l = t & 63;
    int wr = w >> 1, wc = w & 1;
    int lrow = l & 15, lhi = l >> 4;
    int m0 = blockIdx.y * 128, n0 = blockIdx.x * 128;

    f32x4 acc[4][4];
    #pragma unroll
    for (int mi = 0; mi < 4; mi++)
        #pragma unroll
        for (int ni = 0; ni < 4; ni++)
            #pragma unroll
            for (int c = 0; c < 4; c++) acc[mi][ni][c] = 0.f;

    for (int k0 = 0; k0 < K; k0 += 32) {
        __syncthreads();
        #pragma unroll
        for (int r = 0; r < 2; r++) {
            int idx = r*256 + t;
            int row = idx >> 2;
            int cole = (idx & 3) << 3;
            *(short8*)&Asm[row*32 + cole] = *(const short8*)&A[(size_t)(m0 + row)*K + k0 + cole];
            *(short8*)&Bsm[row*32 + cole] = *(const short8*)&Bt[(size_t)(n0 + row)*K + k0 + cole];
        }
        __syncthreads();
        short8 af[4], bfr[4];
        #pragma unroll
        for (int mi = 0; mi < 4; mi++)
            af[mi] = *(short8*)&Asm[(wr*64 + mi*16 + lrow)*32 + lhi*8];
        #pragma unroll
        for (int ni = 0; ni < 4; ni++)
            bfr[ni] = *(short8*)&Bsm[(wc*64 + ni*16 + lrow)*32 + lhi*8];
        #pragma unroll
        for (int mi = 0; mi < 4; mi++)
            #pragma unroll
            for (int ni = 0; ni < 4; ni++)
                acc[mi][ni] = __builtin_amdgcn_mfma_f32_16x16x32_bf16(af[mi], bfr[ni], acc[mi][ni], 0, 0, 0);
    }

    #pragma unroll
    for (int mi = 0; mi < 4; mi++)
        #pragma unroll
        for (int ni = 0; ni < 4; ni++)
            #pragma unroll
            for (int c = 0; c < 4; c++) {
                int row = m0 + wr*64 + mi*16 + lhi*4 + c;
                int col = n0 + wc*64 + ni*16 + lrow;
                float v = acc[mi][ni][c] + bias[col];
                if (OUT_MODE == 0) {
                    ((float*)Cout)[(size_t)row * N + col] = v;
                } else {
                    int b = row >> 11, s = row & 2047;
                    int h = col >> 6,  d = col & 63;
                    ((ushort_t*)Cout)[(size_t)(((b*NHEAD + h)*SSEQ) + s)*HDIM + d] = f2bf(v);
                }
            }
}

// ---------------- flash attention: q,k,v [B,H,S,Dh] bf16 -> o [B,S,E] bf16 ----------------
__global__ __launch_bounds__(256) void flash_attn_kernel(
    const ushort_t* __restrict__ q,
    const ushort_t* __restrict__ k,
    const ushort_t* __restrict__ v,
    ushort_t* __restrict__ o)
{
    __shared__ __attribute__((aligned(16))) ushort_t Ks[64*64];
    __shared__ __attribute__((aligned(16))) ushort_t Vt[64*64];   // [d][kv]
    __shared__ __attribute__((aligned(16))) ushort_t Ps[4][16*64];
    int t = threadIdx.x, w = t >> 6, l = t & 63;
    int lrow = l & 15, lhi = l >> 4;
    int bh = blockIdx.y;            // b*16 + h
    int q0 = blockIdx.x * 64;
    const ushort_t* qp = q + (size_t)bh * SSEQ * HDIM;
    const ushort_t* kp = k + (size_t)bh * SSEQ * HDIM;
    const ushort_t* vp = v + (size_t)bh * SSEQ * HDIM;

    // Q fragments for this wave's 16 rows
    short8 qf[2];
    int qrow = q0 + w*16 + lrow;
    #pragma unroll
    for (int kk = 0; kk < 2; kk++)
        qf[kk] = *(const short8*)&qp[(size_t)qrow*HDIM + kk*32 + lhi*8];

    f32x4 oacc[4];
    float m_run[4], l_run[4];
    #pragma unroll
    for (int i = 0; i < 4; i++) {
        m_run[i] = -1e30f; l_run[i] = 0.f;
        #pragma unroll
        for (int f = 0; f < 4; f++) oacc[f][i] = 0.f;
    }

    for (int kv0 = 0; kv0 < SSEQ; kv0 += 64) {
        __syncthreads();
        #pragma unroll
        for (int r = 0; r < 2; r++) {
            int idx = r*256 + t;
            int row = idx >> 3;            // kv within tile
            int cole = (idx & 7) << 3;     // d
            *(short8*)&Ks[row*64 + cole] = *(const short8*)&kp[(size_t)(kv0 + row)*HDIM + cole];
            short8 vv = *(const short8*)&vp[(size_t)(kv0 + row)*HDIM + cole];
            #pragma unroll
            for (int j = 0; j < 8; j++) Vt[(cole + j)*64 + row] = (ushort_t)vv[j];
        }
        __syncthreads();

        // S = Q K^T
        f32x4 sacc[4];
        #pragma unroll
        for (int f = 0; f < 4; f++)
            #pragma unroll
            for (int c = 0; c < 4; c++) sacc[f][c] = 0.f;
        #pragma unroll
        for (int kk = 0; kk < 2; kk++) {
            #pragma unroll
            for (int f = 0; f < 4; f++) {
                short8 kf = *(short8*)&Ks[(f*16 + lrow)*64 + kk*32 + lhi*8];
                sacc[f] = __builtin_amdgcn_mfma_f32_16x16x32_bf16(qf[kk], kf, sacc[f], 0, 0, 0);
            }
        }
        #pragma unroll
        for (int f = 0; f < 4; f++)
            #pragma unroll
            for (int c = 0; c < 4; c++) sacc[f][c] *= 0.125f;

        // online softmax (rows r = lhi*4 + i, cols f*16 + lrow)
        float alpha[4];
        #pragma unroll
        for (int i = 0; i < 4; i++) {
            float mx = fmaxf(fmaxf(sacc[0][i], sacc[1][i]), fmaxf(sacc[2][i], sacc[3][i]));
            #pragma unroll
            for (int d = 1; d < 16; d <<= 1) mx = fmaxf(mx, __shfl_xor(mx, d));
            float mn = fmaxf(m_run[i], mx);
            alpha[i] = __expf(m_run[i] - mn);
            m_run[i] = mn;
        }
        #pragma unroll
        for (int i = 0; i < 4; i++) {
            float rs = 0.f;
            #pragma unroll
            for (int f = 0; f < 4; f++) {
                float p = __expf(sacc[f][i] - m_run[i]);
                sacc[f][i] = p;
                rs += p;
            }
            #pragma unroll
            for (int d = 1; d < 16; d <<= 1) rs += __shfl_xor(rs, d);
            l_run[i] = l_run[i]*alpha[i] + rs;
            #pragma unroll
            for (int f = 0; f < 4; f++) oacc[f][i] *= alpha[i];
        }
        // P -> LDS (per-wave region, wave-internal ordering)
        #pragma unroll
        for (int f = 0; f < 4; f++)
            #pragma unroll
            for (int i = 0; i < 4; i++)
                Ps[w][(lhi*4 + i)*64 + f*16 + lrow] = f2bf(sacc[f][i]);

        // O += P V
        #pragma unroll
        for (int kk = 0; kk < 2; kk++) {
            short8 pf = *(short8*)&Ps[w][lrow*64 + kk*32 + lhi*8];
            #pragma unroll
            for (int f = 0; f < 4; f++) {
                short8 vf = *(short8*)&Vt[(f*16 + lrow)*64 + kk*32 + lhi*8];
                oacc[f] = __builtin_amdgcn_mfma_f32_16x16x32_bf16(pf, vf, oacc[f], 0, 0, 0);
            }
        }
    }

    int b = bh >> 4, h = bh & 15;
    #pragma unroll
    for (int f = 0; f < 4; f++)
        #pragma unroll
        for (int i = 0; i < 4; i++) {
            int s = q0 + w*16 + lhi*4 + i;
            int d = f*16 + lrow;
            float val = oacc[f][i] / l_run[i];
            o[((size_t)(b*SSEQ + s))*EMBED + h*HDIM + d] = f2bf(val);
        }
}

extern "C" void kernel_launch(void* const* d_in, const int* in_sizes, int n_in,
                              void* d_out, int out_size, void* d_ws, size_t ws_size,
                              hipStream_t stream) {
    const float* x  = (const float*)d_in[0];
    const float* Wq = (const float*)d_in[1];
    const float* bq = (const float*)d_in[2];
    const float* Wk = (const float*)d_in[3];
    const float* bk = (const float*)d_in[4];
    const float* Wv = (const float*)d_in[5];
    const float* bv = (const float*)d_in[6];
    const float* Wo = (const float*)d_in[7];
    const float* bo = (const float*)d_in[8];

    char* ws = (char*)d_ws;
    ushort_t* xb  = (ushort_t*)(ws);                    // 8 MB  x bf16 [4096,1024]
    ushort_t* WqT = (ushort_t*)(ws + (8u  << 20));      // 2 MB
    ushort_t* WkT = (ushort_t*)(ws + (10u << 20));
    ushort_t* WvT = (ushort_t*)(ws + (12u << 20));
    ushort_t* WoT = (ushort_t*)(ws + (14u << 20));
    ushort_t* qb  = (ushort_t*)(ws + (16u << 20));      // 8 MB [B,H,S,Dh]
    ushort_t* kb  = (ushort_t*)(ws + (24u << 20));
    ushort_t* vb  = (ushort_t*)(ws + (32u << 20));
    ushort_t* ab  = (ushort_t*)(ws + (40u << 20));      // 8 MB attn out [B,S,E]

    int nx = MROWS * EMBED;
    cast_bf16_kernel<<<nx/(256*4), 256, 0, stream>>>(x, xb, nx);

    dim3 tb(32, 8), tg(EMBED/32, EMBED/32);
    transpose_cast_kernel<<<tg, tb, 0, stream>>>(Wq, WqT);
    transpose_cast_kernel<<<tg, tb, 0, stream>>>(Wk, WkT);
    transpose_cast_kernel<<<tg, tb, 0, stream>>>(Wv, WvT);
    transpose_cast_kernel<<<tg, tb, 0, stream>>>(Wo, WoT);

    dim3 gg(EMBED/128, MROWS/128);  // (8, 32)
    gemm_bt_kernel<1><<<gg, 256, 0, stream>>>(xb, WqT, bq, qb, MROWS, EMBED, EMBED);
    gemm_bt_kernel<1><<<gg, 256, 0, stream>>>(xb, WkT, bk, kb, MROWS, EMBED, EMBED);
    gemm_bt_kernel<1><<<gg, 256, 0, stream>>>(xb, WvT, bv, vb, MROWS, EMBED, EMBED);

    flash_attn_kernel<<<dim3(SSEQ/64, BB*NHEAD), 256, 0, stream>>>(qb, kb, vb, ab);

    gemm_bt_kernel<0><<<gg, 256, 0, stream>>>(ab, WoT, bo, d_out, MROWS, EMBED, EMBED);
}

// Round 2
// 197.945 us; speedup vs baseline: 1.6100x; 1.6100x over previous
//
#include <hip/hip_runtime.h>
#include <hip/hip_bf16.h>

typedef unsigned short ushort_t;
typedef __attribute__((ext_vector_type(8))) short short8;
typedef __attribute__((ext_vector_type(4))) float f32x4;

#define EMBED 1024
#define NHEAD 16
#define HDIM 64
#define BB 2
#define SSEQ 2048
#define MROWS (BB*SSEQ)          // 4096
#define QKV_N (3*EMBED)          // 3072
#define PER_BUF (MROWS*EMBED)    // 4194304 elems = 8MB bf16

__device__ __forceinline__ ushort_t f2bf(float f) {
    union { float f; unsigned int u; } x; x.f = f;
    unsigned int r = x.u + 0x7fffu + ((x.u >> 16) & 1u);
    return (ushort_t)(r >> 16);
}

__device__ __forceinline__ void gload16(const void* g, void* l) {
    __builtin_amdgcn_global_load_lds(
        (const __attribute__((address_space(1))) unsigned int*)g,
        (__attribute__((address_space(3))) unsigned int*)l, 16, 0, 0);
}

// ---------------- cast x (fp32 -> bf16), vectorized ----------------
__global__ void cast_bf16_kernel(const float* __restrict__ in, ushort_t* __restrict__ out, int n) {
    int i = (blockIdx.x * blockDim.x + threadIdx.x) * 4;
    if (i + 3 < n) {
        float4 v = *(const float4*)(in + i);
        out[i+0] = f2bf(v.x); out[i+1] = f2bf(v.y);
        out[i+2] = f2bf(v.z); out[i+3] = f2bf(v.w);
    }
}

// ---------------- W [K,N] fp32 -> Wt [N,K] bf16, tiled ----------------
__global__ void transpose_cast_kernel(const float* __restrict__ W, ushort_t* __restrict__ Wt) {
    __shared__ float tile[32][33];
    int tx = threadIdx.x, ty = threadIdx.y;   // 32 x 8
    int n0 = blockIdx.x * 32, k0 = blockIdx.y * 32;
    #pragma unroll
    for (int i = 0; i < 4; i++)
        tile[ty*4+i][tx] = W[(size_t)(k0 + ty*4 + i) * EMBED + n0 + tx];
    __syncthreads();
    #pragma unroll
    for (int i = 0; i < 4; i++)
        Wt[(size_t)(n0 + ty*4 + i) * EMBED + k0 + tx] = f2bf(tile[tx][ty*4+i]);
}

// ---------------- V [B,H,S,D] bf16 -> Vt [B,H,D,S] bf16 ----------------
__global__ void transpose_v_kernel(const ushort_t* __restrict__ v, ushort_t* __restrict__ vt) {
    __shared__ ushort_t tile[64][66];   // pad 2 ushorts: row stride 132B -> conflict-free
    int bh = blockIdx.y, s0 = blockIdx.x * 64;
    int t = threadIdx.x;
    int r = t >> 3, c8 = (t & 7) * 8;
    #pragma unroll
    for (int p = 0; p < 2; p++) {
        short8 vv = *(const short8*)&v[((size_t)bh*SSEQ + s0 + p*32 + r)*HDIM + c8];
        #pragma unroll
        for (int j = 0; j < 8; j++) tile[p*32 + r][c8 + j] = (ushort_t)vv[j];
    }
    __syncthreads();
    #pragma unroll
    for (int p = 0; p < 2; p++) {
        int d = p*32 + r;
        short8 ov;
        #pragma unroll
        for (int j = 0; j < 8; j++) ov[j] = (short)tile[c8 + j][d];
        *(short8*)&vt[((size_t)bh*HDIM + d)*SSEQ + s0 + c8] = ov;
    }
}

// ---------------- GEMM: C[M,N] = A[M,K] * Bt[N,K]^T + bias ----------------
// OUT_MODE 0: fp32 row-major C (bias b0).
// OUT_MODE 2: bf16 scatter to q/k/v buffers [B,H,S,Dh]; q pre-scaled by 1/8.
template<int OUT_MODE>
__global__ __launch_bounds__(256) void gemm_bt_kernel(
    const ushort_t* __restrict__ A,   // [M,K] bf16
    const ushort_t* __restrict__ Bt,  // [N,K] bf16
    const float* __restrict__ b0, const float* __restrict__ b1, const float* __restrict__ b2,
    void* __restrict__ Cout,
    int M, int N, int K)
{
    __shared__ __attribute__((aligned(16))) ushort_t Asm[128*32];
    __shared__ __attribute__((aligned(16))) ushort_t Bsm[128*32];
    int t = threadIdx.x;
    int w = t >> 6, l = t & 63;
    int wr = w >> 1, wc = w & 1;
    int lrow = l & 15, lhi = l >> 4;
    int m0 = blockIdx.y * 128, n0 = blockIdx.x * 128;
    int srow = l >> 2;            // 0..15 within 16-row chunk
    int scol = (l & 3) * 8;       // element offset of 16B chunk

    f32x4 acc[4][4];
    #pragma unroll
    for (int mi = 0; mi < 4; mi++)
        #pragma unroll
        for (int ni = 0; ni < 4; ni++)
            #pragma unroll
            for (int c = 0; c < 4; c++) acc[mi][ni][c] = 0.f;

    for (int k0 = 0; k0 < K; k0 += 32) {
        __syncthreads();
        #pragma unroll
        for (int p = 0; p < 2; p++) {
            gload16(&A [(size_t)(m0 + w*32 + p*16 + srow)*K + k0 + scol], &Asm[(w*32 + p*16)*32]);
            gload16(&Bt[(size_t)(n0 + w*32 + p*16 + srow)*K + k0 + scol], &Bsm[(w*32 + p*16)*32]);
        }
        __syncthreads();
        short8 af[4], bfr[4];
        #pragma unroll
        for (int mi = 0; mi < 4; mi++)
            af[mi] = *(short8*)&Asm[(wr*64 + mi*16 + lrow)*32 + lhi*8];
        #pragma unroll
        for (int ni = 0; ni < 4; ni++)
            bfr[ni] = *(short8*)&Bsm[(wc*64 + ni*16 + lrow)*32 + lhi*8];
        #pragma unroll
        for (int mi = 0; mi < 4; mi++)
            #pragma unroll
            for (int ni = 0; ni < 4; ni++)
                acc[mi][ni] = __builtin_amdgcn_mfma_f32_16x16x32_bf16(af[mi], bfr[ni], acc[mi][ni], 0, 0, 0);
    }

    #pragma unroll
    for (int mi = 0; mi < 4; mi++)
        #pragma unroll
        for (int ni = 0; ni < 4; ni++) {
            int col = n0 + wc*64 + ni*16 + lrow;
            #pragma unroll
            for (int c = 0; c < 4; c++) {
                int row = m0 + wr*64 + mi*16 + lhi*4 + c;
                if (OUT_MODE == 0) {
                    float v = acc[mi][ni][c] + b0[col];
                    ((float*)Cout)[(size_t)row * N + col] = v;
                } else {
                    int which = col >> 10, hc = col & 1023;
                    const float* bp = (which == 0) ? b0 : (which == 1) ? b1 : b2;
                    float v = acc[mi][ni][c] + bp[hc];
                    if (which == 0) v *= 0.125f;   // fold attention scale into Q (exact)
                    int h = hc >> 6, d = hc & 63;
                    int b = row >> 11, s = row & 2047;
                    ((ushort_t*)Cout)[(size_t)which*PER_BUF + ((size_t)((b*NHEAD + h)*SSEQ) + s)*HDIM + d] = f2bf(v);
                }
            }
        }
}

// ---------------- flash attention ----------------
// q,k: [B,H,S,D] bf16 (q pre-scaled by 1/8); vt: [B,H,D,S] bf16; o: [B,S,E] bf16
__global__ __launch_bounds__(256) void flash_attn_kernel(
    const ushort_t* __restrict__ q,
    const ushort_t* __restrict__ k,
    const ushort_t* __restrict__ vt,
    ushort_t* __restrict__ o)
{
    __shared__ __attribute__((aligned(16))) ushort_t Ks[64*64];   // [kv][d], XOR-swizzled
    __shared__ __attribute__((aligned(16))) ushort_t Vs[64*64];   // [d][kv], XOR-swizzled
    __shared__ __attribute__((aligned(16))) ushort_t Ps[4][16*64];// per-wave [q][kv], swizzled
    int t = threadIdx.x, w = t >> 6, l = t & 63;
    int lrow = l & 15, lhi = l >> 4;
    int bh = blockIdx.y;
    int q0 = blockIdx.x * 64;
    const ushort_t* qp = q  + (size_t)bh * SSEQ * HDIM;
    const ushort_t* kp = k  + (size_t)bh * SSEQ * HDIM;
    const ushort_t* vp = vt + (size_t)bh * HDIM * SSEQ;

    short8 qf[2];
    int qrow = q0 + w*16 + lrow;
    #pragma unroll
    for (int kk = 0; kk < 2; kk++)
        qf[kk] = *(const short8*)&qp[(size_t)qrow*HDIM + kk*32 + lhi*8];

    f32x4 oacc[4];
    float m_run[4], l_run[4];
    #pragma unroll
    for (int i = 0; i < 4; i++) {
        m_run[i] = -1e30f; l_run[i] = 0.f;
        #pragma unroll
        for (int f = 0; f < 4; f++) oacc[f][i] = 0.f;
    }

    for (int kv0 = 0; kv0 < SSEQ; kv0 += 64) {
        __syncthreads();
        #pragma unroll
        for (int p = 0; p < 2; p++) {
            int idx = p*256 + t;
            int row = idx >> 3;            // kv idx for K, d idx for Vt
            int cole = (idx & 7) << 3;
            int sw = cole ^ ((row & 7) << 3);
            *(short8*)&Ks[row*64 + sw] = *(const short8*)&kp[(size_t)(kv0 + row)*HDIM + cole];
            *(short8*)&Vs[row*64 + sw] = *(const short8*)&vp[(size_t)row*SSEQ + kv0 + cole];
        }
        __syncthreads();

        // S = Q K^T  (q pre-scaled)
        f32x4 sacc[4];
        #pragma unroll
        for (int f = 0; f < 4; f++)
            #pragma unroll
            for (int c = 0; c < 4; c++) sacc[f][c] = 0.f;
        #pragma unroll
        for (int kk = 0; kk < 2; kk++) {
            #pragma unroll
            for (int f = 0; f < 4; f++) {
                int r = f*16 + lrow;
                short8 kf = *(short8*)&Ks[r*64 + ((kk*32 + lhi*8) ^ ((r & 7) << 3))];
                sacc[f] = __builtin_amdgcn_mfma_f32_16x16x32_bf16(qf[kk], kf, sacc[f], 0, 0, 0);
            }
        }

        // online softmax; lane holds rows q=lhi*4+i, cols kv=f*16+lrow
        float alpha[4];
        #pragma unroll
        for (int i = 0; i < 4; i++) {
            float mx = fmaxf(fmaxf(sacc[0][i], sacc[1][i]), fmaxf(sacc[2][i], sacc[3][i]));
            #pragma unroll
            for (int d = 1; d < 16; d <<= 1) mx = fmaxf(mx, __shfl_xor(mx, d));
            float mn = fmaxf(m_run[i], mx);
            alpha[i] = __expf(m_run[i] - mn);
            m_run[i] = mn;
        }
        #pragma unroll
        for (int i = 0; i < 4; i++) {
            float rs = 0.f;
            #pragma unroll
            for (int f = 0; f < 4; f++) {
                float p = __expf(sacc[f][i] - m_run[i]);
                sacc[f][i] = p;
                rs += p;
            }
            #pragma unroll
            for (int d = 1; d < 16; d <<= 1) rs += __shfl_xor(rs, d);
            l_run[i] = l_run[i]*alpha[i] + rs;
            #pragma unroll
            for (int f = 0; f < 4; f++) oacc[f][i] *= alpha[i];
        }

        // P -> LDS (per-wave region, swizzled)
        #pragma unroll
        for (int f = 0; f < 4; f++)
            #pragma unroll
            for (int i = 0; i < 4; i++) {
                int qr = lhi*4 + i;
                Ps[w][qr*64 + ((f*16 + lrow) ^ ((qr & 7) << 3))] = f2bf(sacc[f][i]);
            }

        // O += P V
        #pragma unroll
        for (int kk = 0; kk < 2; kk++) {
            short8 pf = *(short8*)&Ps[w][lrow*64 + ((kk*32 + lhi*8) ^ ((lrow & 7) << 3))];
            #pragma unroll
            for (int f = 0; f < 4; f++) {
                int r = f*16 + lrow;
                short8 vf = *(short8*)&Vs[r*64 + ((kk*32 + lhi*8) ^ ((r & 7) << 3))];
                oacc[f] = __builtin_amdgcn_mfma_f32_16x16x32_bf16(pf, vf, oacc[f], 0, 0, 0);
            }
        }
    }

    int b = bh >> 4, h = bh & 15;
    float rl[4];
    #pragma unroll
    for (int i = 0; i < 4; i++) rl[i] = 1.0f / l_run[i];
    #pragma unroll
    for (int f = 0; f < 4; f++)
        #pragma unroll
        for (int i = 0; i < 4; i++) {
            int s = q0 + w*16 + lhi*4 + i;
            int d = f*16 + lrow;
            o[((size_t)(b*SSEQ + s))*EMBED + h*HDIM + d] = f2bf(oacc[f][i] * rl[i]);
        }
}

extern "C" void kernel_launch(void* const* d_in, const int* in_sizes, int n_in,
                              void* d_out, int out_size, void* d_ws, size_t ws_size,
                              hipStream_t stream) {
    const float* x  = (const float*)d_in[0];
    const float* Wq = (const float*)d_in[1];
    const float* bq = (const float*)d_in[2];
    const float* Wk = (const float*)d_in[3];
    const float* bk = (const float*)d_in[4];
    const float* Wv = (const float*)d_in[5];
    const float* bv = (const float*)d_in[6];
    const float* Wo = (const float*)d_in[7];
    const float* bo = (const float*)d_in[8];

    char* ws = (char*)d_ws;
    ushort_t* xb  = (ushort_t*)(ws);                    // 0-8 MB: x bf16, later reused as attn-out
    ushort_t* WqT = (ushort_t*)(ws + (8u  << 20));      // 8-16 MB: WqT|WkT|WvT contiguous [3072][1024], WoT
    ushort_t* WkT = (ushort_t*)(ws + (10u << 20));
    ushort_t* WvT = (ushort_t*)(ws + (12u << 20));
    ushort_t* WoT = (ushort_t*)(ws + (14u << 20));
    ushort_t* qb  = (ushort_t*)(ws + (16u << 20));      // q|k|v contiguous, 8 MB each
    ushort_t* kb  = (ushort_t*)(ws + (24u << 20));
    ushort_t* vb  = (ushort_t*)(ws + (32u << 20));
    ushort_t* vtb = (ushort_t*)(ws + (40u << 20));      // V transposed [B,H,D,S]
    ushort_t* ab  = xb;                                 // attn out reuses xb region

    int nx = MROWS * EMBED;
    cast_bf16_kernel<<<nx/(256*4), 256, 0, stream>>>(x, xb, nx);

    dim3 tb(32, 8), tg(EMBED/32, EMBED/32);
    transpose_cast_kernel<<<tg, tb, 0, stream>>>(Wq, WqT);
    transpose_cast_kernel<<<tg, tb, 0, stream>>>(Wk, WkT);
    transpose_cast_kernel<<<tg, tb, 0, stream>>>(Wv, WvT);
    transpose_cast_kernel<<<tg, tb, 0, stream>>>(Wo, WoT);

    // fused QKV projection: [4096,1024] x [3072,1024]^T
    gemm_bt_kernel<2><<<dim3(QKV_N/128, MROWS/128), 256, 0, stream>>>(
        xb, WqT, bq, bk, bv, qb, MROWS, QKV_N, EMBED);

    transpose_v_kernel<<<dim3(SSEQ/64, BB*NHEAD), 256, 0, stream>>>(vb, vtb);

    flash_attn_kernel<<<dim3(SSEQ/64, BB*NHEAD), 256, 0, stream>>>(qb, kb, vtb, ab);

    gemm_bt_kernel<0><<<dim3(EMBED/128, MROWS/128), 256, 0, stream>>>(
        ab, WoT, bo, bo, bo, d_out, MROWS, EMBED, EMBED);
}

// Round 4
// 146.031 us; speedup vs baseline: 2.1824x; 1.3555x over previous
//
#include <hip/hip_runtime.h>
#include <hip/hip_bf16.h>

typedef unsigned short ushort_t;
typedef __attribute__((ext_vector_type(8))) short short8;
typedef __attribute__((ext_vector_type(4))) float f32x4;
typedef __attribute__((ext_vector_type(16))) float f32x16;
typedef __attribute__((ext_vector_type(2))) unsigned int uint2v;

#define EMBED 1024
#define NHEAD 16
#define HDIM 64
#define BB 2
#define SSEQ 2048
#define MROWS (BB*SSEQ)          // 4096
#define QKV_N (3*EMBED)          // 3072
#define PER_BUF (MROWS*EMBED)    // 4194304 elems = 8MB bf16

__device__ __forceinline__ ushort_t f2bf(float f) {
    union { float f; unsigned int u; } x; x.f = f;
    unsigned int r = x.u + 0x7fffu + ((x.u >> 16) & 1u);
    return (ushort_t)(r >> 16);
}
__device__ __forceinline__ unsigned pack2bf(float lo, float hi) {
    return (unsigned)f2bf(lo) | ((unsigned)f2bf(hi) << 16);
}

__device__ __forceinline__ void gload16(const void* g, void* l) {
    __builtin_amdgcn_global_load_lds(
        (const __attribute__((address_space(1))) unsigned int*)g,
        (__attribute__((address_space(3))) unsigned int*)l, 16, 0, 0);
}

// ---------------- cast x (fp32 -> bf16), vectorized ----------------
__global__ void cast_bf16_kernel(const float* __restrict__ in, ushort_t* __restrict__ out, int n) {
    int i = (blockIdx.x * blockDim.x + threadIdx.x) * 4;
    if (i + 3 < n) {
        float4 v = *(const float4*)(in + i);
        out[i+0] = f2bf(v.x); out[i+1] = f2bf(v.y);
        out[i+2] = f2bf(v.z); out[i+3] = f2bf(v.w);
    }
}

// ---------------- W [K,N] fp32 -> Wt [N,K] bf16, tiled ----------------
__global__ void transpose_cast_kernel(const float* __restrict__ W, ushort_t* __restrict__ Wt) {
    __shared__ float tile[32][33];
    int tx = threadIdx.x, ty = threadIdx.y;   // 32 x 8
    int n0 = blockIdx.x * 32, k0 = blockIdx.y * 32;
    #pragma unroll
    for (int i = 0; i < 4; i++)
        tile[ty*4+i][tx] = W[(size_t)(k0 + ty*4 + i) * EMBED + n0 + tx];
    __syncthreads();
    #pragma unroll
    for (int i = 0; i < 4; i++)
        Wt[(size_t)(n0 + ty*4 + i) * EMBED + k0 + tx] = f2bf(tile[tx][ty*4+i]);
}

// ---------------- V [B,H,S,D] bf16 -> Vt [B,H,D,S] bf16 ----------------
__global__ void transpose_v_kernel(const ushort_t* __restrict__ v, ushort_t* __restrict__ vt) {
    __shared__ ushort_t tile[64][66];
    int bh = blockIdx.y, s0 = blockIdx.x * 64;
    int t = threadIdx.x;
    int r = t >> 3, c8 = (t & 7) * 8;
    #pragma unroll
    for (int p = 0; p < 2; p++) {
        short8 vv = *(const short8*)&v[((size_t)bh*SSEQ + s0 + p*32 + r)*HDIM + c8];
        #pragma unroll
        for (int j = 0; j < 8; j++) tile[p*32 + r][c8 + j] = (ushort_t)vv[j];
    }
    __syncthreads();
    #pragma unroll
    for (int p = 0; p < 2; p++) {
        int d = p*32 + r;
        short8 ov;
        #pragma unroll
        for (int j = 0; j < 8; j++) ov[j] = (short)tile[c8 + j][d];
        *(short8*)&vt[((size_t)bh*HDIM + d)*SSEQ + s0 + c8] = ov;
    }
}

// ---------------- GEMM: C[M,N] = A[M,K] * Bt[N,K]^T + bias ----------------
// OUT_MODE 0: fp32 row-major C (bias b0).
// OUT_MODE 2: bf16 scatter to q/k/v buffers [B,H,S,Dh]; q pre-scaled by 0.125*log2(e).
template<int OUT_MODE>
__global__ __launch_bounds__(256) void gemm_bt_kernel(
    const ushort_t* __restrict__ A,   // [M,K] bf16
    const ushort_t* __restrict__ Bt,  // [N,K] bf16
    const float* __restrict__ b0, const float* __restrict__ b1, const float* __restrict__ b2,
    void* __restrict__ Cout,
    int M, int N, int K)
{
    __shared__ __attribute__((aligned(16))) ushort_t Asm[128*32];
    __shared__ __attribute__((aligned(16))) ushort_t Bsm[128*32];
    int t = threadIdx.x;
    int w = t >> 6, l = t & 63;
    int wr = w >> 1, wc = w & 1;
    int lrow = l & 15, lhi = l >> 4;
    int m0 = blockIdx.y * 128, n0 = blockIdx.x * 128;
    int srow = l >> 2;
    int scol = (l & 3) * 8;

    f32x4 acc[4][4];
    #pragma unroll
    for (int mi = 0; mi < 4; mi++)
        #pragma unroll
        for (int ni = 0; ni < 4; ni++)
            #pragma unroll
            for (int c = 0; c < 4; c++) acc[mi][ni][c] = 0.f;

    for (int k0 = 0; k0 < K; k0 += 32) {
        __syncthreads();
        #pragma unroll
        for (int p = 0; p < 2; p++) {
            gload16(&A [(size_t)(m0 + w*32 + p*16 + srow)*K + k0 + scol], &Asm[(w*32 + p*16)*32]);
            gload16(&Bt[(size_t)(n0 + w*32 + p*16 + srow)*K + k0 + scol], &Bsm[(w*32 + p*16)*32]);
        }
        __syncthreads();
        short8 af[4], bfr[4];
        #pragma unroll
        for (int mi = 0; mi < 4; mi++)
            af[mi] = *(short8*)&Asm[(wr*64 + mi*16 + lrow)*32 + lhi*8];
        #pragma unroll
        for (int ni = 0; ni < 4; ni++)
            bfr[ni] = *(short8*)&Bsm[(wc*64 + ni*16 + lrow)*32 + lhi*8];
        #pragma unroll
        for (int mi = 0; mi < 4; mi++)
            #pragma unroll
            for (int ni = 0; ni < 4; ni++)
                acc[mi][ni] = __builtin_amdgcn_mfma_f32_16x16x32_bf16(af[mi], bfr[ni], acc[mi][ni], 0, 0, 0);
    }

    #pragma unroll
    for (int mi = 0; mi < 4; mi++)
        #pragma unroll
        for (int ni = 0; ni < 4; ni++) {
            int col = n0 + wc*64 + ni*16 + lrow;
            #pragma unroll
            for (int c = 0; c < 4; c++) {
                int row = m0 + wr*64 + mi*16 + lhi*4 + c;
                if (OUT_MODE == 0) {
                    float v = acc[mi][ni][c] + b0[col];
                    ((float*)Cout)[(size_t)row * N + col] = v;
                } else {
                    int which = col >> 10, hc = col & 1023;
                    const float* bp = (which == 0) ? b0 : (which == 1) ? b1 : b2;
                    float v = acc[mi][ni][c] + bp[hc];
                    if (which == 0) v *= 0.18033688011112042f;  // 0.125 * log2(e)
                    int h = hc >> 6, d = hc & 63;
                    int b = row >> 11, s = row & 2047;
                    ((ushort_t*)Cout)[(size_t)which*PER_BUF + ((size_t)((b*NHEAD + h)*SSEQ) + s)*HDIM + d] = f2bf(v);
                }
            }
        }
}

// ---------------- flash attention v2: swapped QK^T, 32x32 MFMA ----------------
// q: [B,H,S,D] bf16 pre-scaled by 0.125*log2e; k: [B,H,S,D]; vt: [B,H,D,S]; o: [B,S,E] bf16
#define MFMA32(a,b,c) __builtin_amdgcn_mfma_f32_32x32x16_bf16(a, b, c, 0, 0, 0)

__global__ __launch_bounds__(256, 2) void flash_attn2_kernel(
    const ushort_t* __restrict__ q,
    const ushort_t* __restrict__ k,
    const ushort_t* __restrict__ vt,
    ushort_t* __restrict__ o)
{
    __shared__ __attribute__((aligned(16))) ushort_t Ks[2][64*64];  // [kv][d] swizzled
    __shared__ __attribute__((aligned(16))) ushort_t Vs[2][64*64];  // [d][kv] swizzled

    int t = threadIdx.x, w = t >> 6, l = t & 63;
    int l31 = l & 31, hi = l >> 5;

    // XCD-bijective swizzle: 512 wgs, 64/XCD -> 4 whole heads per XCD L2
    int flat = blockIdx.x;
    int wg = (flat & 7) * 64 + (flat >> 3);
    int bh = wg >> 4;
    int q0 = (wg & 15) * 128;

    const ushort_t* qp = q  + (size_t)bh * SSEQ * HDIM;
    const ushort_t* kp = k  + (size_t)bh * SSEQ * HDIM;
    const ushort_t* vp = vt + (size_t)bh * HDIM * SSEQ;

    int lr = l >> 3, lc = l & 7;
    int colel = 8 * (lc ^ lr);   // pre-swizzled global column for staging

    // Q fragments (B-operand): lane holds Q[q0 + w*32 + l31][st*16 + hi*8 + j]
    short8 qf[4];
    int qrow = q0 + w*32 + l31;
    #pragma unroll
    for (int st = 0; st < 4; st++)
        qf[st] = *(const short8*)&qp[(size_t)qrow*HDIM + st*16 + hi*8];

    f32x16 o0 = {}, o1 = {};
    float m_run = -1e30f, l_run = 0.f;

    // stage K rows and Vt rows [w*16, w*16+16) of the 64x64 tiles
    #define STAGE(buf, kv0) { \
        _Pragma("unroll") \
        for (int c = 0; c < 2; c++) { \
            int row = w*16 + c*8 + lr; \
            gload16(&kp[(size_t)(kv0 + row)*HDIM + colel], &Ks[buf][(w*16 + c*8)*64]); \
            gload16(&vp[(size_t)row*SSEQ + (kv0) + colel], &Vs[buf][(w*16 + c*8)*64]); \
        } }

    STAGE(0, 0)
    asm volatile("s_waitcnt vmcnt(0)");
    __syncthreads();
    int cur = 0;

    for (int kv0 = 0; kv0 < SSEQ; kv0 += 64) {
        if (kv0 + 64 < SSEQ) { STAGE(cur ^ 1, kv0 + 64) }

        // ---- S^T = K @ Q^T : lane holds S[q=l31][kv=crow(r,hi)+32*kt]
        f32x16 s0 = {}, s1 = {};
        #pragma unroll
        for (int st = 0; st < 4; st++) {
            int colb = st*16 + hi*8;
            short8 kf0 = *(const short8*)&Ks[cur][l31*64        + (colb ^ ((l31 & 7) << 3))];
            short8 kf1 = *(const short8*)&Ks[cur][(32 + l31)*64 + (colb ^ ((l31 & 7) << 3))];
            s0 = MFMA32(kf0, qf[st], s0);
            s1 = MFMA32(kf1, qf[st], s1);
        }

        // ---- online softmax (log2 domain), per-lane rows
        float mx = s0[0];
        #pragma unroll
        for (int r = 1; r < 16; r++) mx = fmaxf(mx, s0[r]);
        #pragma unroll
        for (int r = 0; r < 16; r++) mx = fmaxf(mx, s1[r]);
        mx = fmaxf(mx, __shfl_xor(mx, 32));

        if (__any(mx > m_run + 8.f)) {       // defer-max (T13)
            float mnew = fmaxf(m_run, mx);
            float alpha = __builtin_amdgcn_exp2f(m_run - mnew);
            #pragma unroll
            for (int r = 0; r < 16; r++) { o0[r] *= alpha; o1[r] *= alpha; }
            l_run *= alpha;
            m_run = mnew;
        }
        float rs = 0.f;
        #pragma unroll
        for (int r = 0; r < 16; r++) { s0[r] = __builtin_amdgcn_exp2f(s0[r] - m_run); rs += s0[r]; }
        #pragma unroll
        for (int r = 0; r < 16; r++) { s1[r] = __builtin_amdgcn_exp2f(s1[r] - m_run); rs += s1[r]; }
        rs += __shfl_xor(rs, 32);
        l_run += rs;

        // ---- P -> bf16 B-fragments via pack + permlane32_swap (T12)
        // pfr[ks][j] = P[q=l31][kv = 16*ks + 8*hi + j]
        // swap(a,b): .x = {lo:a_lo, hi:b_lo}, .y = {lo:a_hi, hi:b_hi}  (vdst-upper <-> vsrc-lower)
        short8 pfr[4];
        #pragma unroll
        for (int kt = 0; kt < 2; kt++) {
            #pragma unroll
            for (int sub = 0; sub < 2; sub++) {
                float e0, e1, e2, e3, e4, e5, e6, e7;
                if (kt == 0 && sub == 0) { e0=s0[0];e1=s0[1];e2=s0[2];e3=s0[3];e4=s0[4];e5=s0[5];e6=s0[6];e7=s0[7]; }
                else if (kt == 0)        { e0=s0[8];e1=s0[9];e2=s0[10];e3=s0[11];e4=s0[12];e5=s0[13];e6=s0[14];e7=s0[15]; }
                else if (sub == 0)       { e0=s1[0];e1=s1[1];e2=s1[2];e3=s1[3];e4=s1[4];e5=s1[5];e6=s1[6];e7=s1[7]; }
                else                     { e0=s1[8];e1=s1[9];e2=s1[10];e3=s1[11];e4=s1[12];e5=s1[13];e6=s1[14];e7=s1[15]; }
                unsigned a0 = pack2bf(e0, e1);   // regs 0,1  (crow 0,1 of quad)
                unsigned a1 = pack2bf(e2, e3);   // regs 2,3
                unsigned b0 = pack2bf(e4, e5);   // regs 4,5
                unsigned b1 = pack2bf(e6, e7);   // regs 6,7
                uint2v r0 = __builtin_amdgcn_permlane32_swap(a0, b0, false, false);
                uint2v r1 = __builtin_amdgcn_permlane32_swap(a1, b1, false, false);
                union { unsigned u[4]; short8 v; } pf;
                pf.u[0] = r0.x; pf.u[1] = r1.x; pf.u[2] = r0.y; pf.u[3] = r1.y;
                pfr[kt*2 + sub] = pf.v;
            }
        }

        // ---- O^T += V^T P^T : lane holds O[q=l31][d=crow(r,hi)+32*dt]
        #pragma unroll
        for (int ks = 0; ks < 4; ks++) {
            int colb = ks*16 + hi*8;
            short8 vf0 = *(const short8*)&Vs[cur][l31*64        + (colb ^ ((l31 & 7) << 3))];
            short8 vf1 = *(const short8*)&Vs[cur][(32 + l31)*64 + (colb ^ ((l31 & 7) << 3))];
            o0 = MFMA32(vf0, pfr[ks], o0);
            o1 = MFMA32(vf1, pfr[ks], o1);
        }

        asm volatile("s_waitcnt vmcnt(0)");
        __syncthreads();
        cur ^= 1;
    }

    // ---- epilogue: normalize, LDS roundtrip for coalesced stores
    float rl = 1.f / l_run;
    ushort_t* Ot = ((ushort_t*)Ks) + w*(32*64);   // per-wave 4KB
    #pragma unroll
    for (int dt = 0; dt < 2; dt++)
        #pragma unroll
        for (int rq = 0; rq < 4; rq++) {
            float v0 = (dt ? o1[rq*4+0] : o0[rq*4+0]) * rl;
            float v1 = (dt ? o1[rq*4+1] : o0[rq*4+1]) * rl;
            float v2 = (dt ? o1[rq*4+2] : o0[rq*4+2]) * rl;
            float v3 = (dt ? o1[rq*4+3] : o0[rq*4+3]) * rl;
            int d0 = dt*32 + rq*8 + hi*4;
            uint2v pw = { pack2bf(v0, v1), pack2bf(v2, v3) };
            *(uint2v*)&Ot[l31*64 + (d0 ^ ((l31 & 7) << 3))] = pw;
        }

    int b = bh >> 4, h = bh & 15;
    int q2 = l >> 1, dh = (l & 1) * 32;
    size_t obase = ((size_t)(b*SSEQ) + q0 + w*32 + q2)*EMBED + h*HDIM;
    #pragma unroll
    for (int j = 0; j < 4; j++) {
        int d = dh + j*8;
        short8 ov = *(short8*)&Ot[q2*64 + (d ^ ((q2 & 7) << 3))];
        *(short8*)&o[obase + d] = ov;
    }
}

extern "C" void kernel_launch(void* const* d_in, const int* in_sizes, int n_in,
                              void* d_out, int out_size, void* d_ws, size_t ws_size,
                              hipStream_t stream) {
    const float* x  = (const float*)d_in[0];
    const float* Wq = (const float*)d_in[1];
    const float* bq = (const float*)d_in[2];
    const float* Wk = (const float*)d_in[3];
    const float* bk = (const float*)d_in[4];
    const float* Wv = (const float*)d_in[5];
    const float* bv = (const float*)d_in[6];
    const float* Wo = (const float*)d_in[7];
    const float* bo = (const float*)d_in[8];

    char* ws = (char*)d_ws;
    ushort_t* xb  = (ushort_t*)(ws);                    // 0-8 MB: x bf16, later reused as attn-out
    ushort_t* WqT = (ushort_t*)(ws + (8u  << 20));      // WqT|WkT|WvT contiguous [3072][1024]
    ushort_t* WkT = (ushort_t*)(ws + (10u << 20));
    ushort_t* WvT = (ushort_t*)(ws + (12u << 20));
    ushort_t* WoT = (ushort_t*)(ws + (14u << 20));
    ushort_t* qb  = (ushort_t*)(ws + (16u << 20));      // q|k|v contiguous, 8 MB each
    ushort_t* kb  = (ushort_t*)(ws + (24u << 20));
    ushort_t* vb  = (ushort_t*)(ws + (32u << 20));
    ushort_t* vtb = (ushort_t*)(ws + (40u << 20));      // V transposed [B,H,D,S]
    ushort_t* ab  = xb;

    int nx = MROWS * EMBED;
    cast_bf16_kernel<<<nx/(256*4), 256, 0, stream>>>(x, xb, nx);

    dim3 tb(32, 8), tg(EMBED/32, EMBED/32);
    transpose_cast_kernel<<<tg, tb, 0, stream>>>(Wq, WqT);
    transpose_cast_kernel<<<tg, tb, 0, stream>>>(Wk, WkT);
    transpose_cast_kernel<<<tg, tb, 0, stream>>>(Wv, WvT);
    transpose_cast_kernel<<<tg, tb, 0, stream>>>(Wo, WoT);

    gemm_bt_kernel<2><<<dim3(QKV_N/128, MROWS/128), 256, 0, stream>>>(
        xb, WqT, bq, bk, bv, qb, MROWS, QKV_N, EMBED);

    transpose_v_kernel<<<dim3(SSEQ/64, BB*NHEAD), 256, 0, stream>>>(vb, vtb);

    flash_attn2_kernel<<<512, 256, 0, stream>>>(qb, kb, vtb, ab);

    gemm_bt_kernel<0><<<dim3(EMBED/128, MROWS/128), 256, 0, stream>>>(
        ab, WoT, bo, bo, bo, d_out, MROWS, EMBED, EMBED);
}

// Round 6
// 132.782 us; speedup vs baseline: 2.4002x; 1.0998x over previous
//
#include <hip/hip_runtime.h>
#include <hip/hip_bf16.h>

typedef unsigned short ushort_t;
typedef __attribute__((ext_vector_type(8))) short short8;
typedef __attribute__((ext_vector_type(4))) float f32x4;
typedef __attribute__((ext_vector_type(16))) float f32x16;
typedef __attribute__((ext_vector_type(2))) unsigned int uint2v;

#define EMBED 1024
#define NHEAD 16
#define HDIM 64
#define BB 2
#define SSEQ 2048
#define MROWS (BB*SSEQ)          // 4096
#define QKV_N (3*EMBED)          // 3072
#define PER_BUF (MROWS*EMBED)    // 4194304 elems = 8MB bf16

__device__ __forceinline__ ushort_t f2bf(float f) {
    union { float f; unsigned int u; } x; x.f = f;
    unsigned int r = x.u + 0x7fffu + ((x.u >> 16) & 1u);
    return (ushort_t)(r >> 16);
}
// HW packed f32x2 -> bf16x2 (RNE), single VALU op
__device__ __forceinline__ unsigned cvt_pk_bf16(float lo, float hi) {
    unsigned r;
    asm("v_cvt_pk_bf16_f32 %0, %1, %2" : "=v"(r) : "v"(lo), "v"(hi));
    return r;
}

__device__ __forceinline__ void gload16(const void* g, void* l) {
    __builtin_amdgcn_global_load_lds(
        (const __attribute__((address_space(1))) unsigned int*)g,
        (__attribute__((address_space(3))) unsigned int*)l, 16, 0, 0);
}

// ---------------- cast x (fp32 -> bf16), vectorized ----------------
__global__ void cast_bf16_kernel(const float* __restrict__ in, ushort_t* __restrict__ out, int n) {
    int i = (blockIdx.x * blockDim.x + threadIdx.x) * 4;
    if (i + 3 < n) {
        float4 v = *(const float4*)(in + i);
        out[i+0] = f2bf(v.x); out[i+1] = f2bf(v.y);
        out[i+2] = f2bf(v.z); out[i+3] = f2bf(v.w);
    }
}

// ---------------- 4x W [K,N] fp32 -> Wt [N,K] bf16, one launch ----------------
__global__ void transpose_cast4_kernel(
    const float* __restrict__ W0, const float* __restrict__ W1,
    const float* __restrict__ W2, const float* __restrict__ W3,
    ushort_t* __restrict__ T0, ushort_t* __restrict__ T1,
    ushort_t* __restrict__ T2, ushort_t* __restrict__ T3)
{
    __shared__ float tile[32][33];
    int z = blockIdx.z;
    const float* W = (z == 0) ? W0 : (z == 1) ? W1 : (z == 2) ? W2 : W3;
    ushort_t* Wt   = (z == 0) ? T0 : (z == 1) ? T1 : (z == 2) ? T2 : T3;
    int tx = threadIdx.x, ty = threadIdx.y;   // 32 x 8
    int n0 = blockIdx.x * 32, k0 = blockIdx.y * 32;
    #pragma unroll
    for (int i = 0; i < 4; i++)
        tile[ty*4+i][tx] = W[(size_t)(k0 + ty*4 + i) * EMBED + n0 + tx];
    __syncthreads();
    #pragma unroll
    for (int i = 0; i < 4; i++)
        Wt[(size_t)(n0 + ty*4 + i) * EMBED + k0 + tx] = f2bf(tile[tx][ty*4+i]);
}

// ---------------- V [B,H,S,D] bf16 -> Vt [B,H,D,S] bf16 ----------------
__global__ void transpose_v_kernel(const ushort_t* __restrict__ v, ushort_t* __restrict__ vt) {
    __shared__ ushort_t tile[64][66];
    int bh = blockIdx.y, s0 = blockIdx.x * 64;
    int t = threadIdx.x;
    int r = t >> 3, c8 = (t & 7) * 8;
    #pragma unroll
    for (int p = 0; p < 2; p++) {
        short8 vv = *(const short8*)&v[((size_t)bh*SSEQ + s0 + p*32 + r)*HDIM + c8];
        #pragma unroll
        for (int j = 0; j < 8; j++) tile[p*32 + r][c8 + j] = (ushort_t)vv[j];
    }
    __syncthreads();
    #pragma unroll
    for (int p = 0; p < 2; p++) {
        int d = p*32 + r;
        short8 ov;
        #pragma unroll
        for (int j = 0; j < 8; j++) ov[j] = (short)tile[c8 + j][d];
        *(short8*)&vt[((size_t)bh*HDIM + d)*SSEQ + s0 + c8] = ov;
    }
}

// ---------------- GEMM: C[M,N] = A[M,K] * Bt[N,K]^T + bias ----------------
// OUT_MODE 0: fp32 row-major C (bias b0).
// OUT_MODE 2: bf16 scatter to q/k/v buffers [B,H,S,Dh]; q pre-scaled by 0.125*log2(e).
template<int OUT_MODE>
__global__ __launch_bounds__(256) void gemm_bt_kernel(
    const ushort_t* __restrict__ A,   // [M,K] bf16
    const ushort_t* __restrict__ Bt,  // [N,K] bf16
    const float* __restrict__ b0, const float* __restrict__ b1, const float* __restrict__ b2,
    void* __restrict__ Cout,
    int M, int N, int K)
{
    __shared__ __attribute__((aligned(16))) ushort_t Asm[128*32];
    __shared__ __attribute__((aligned(16))) ushort_t Bsm[128*32];
    int t = threadIdx.x;
    int w = t >> 6, l = t & 63;
    int wr = w >> 1, wc = w & 1;
    int lrow = l & 15, lhi = l >> 4;

    // XCD-chunked bijective swizzle: each XCD gets nwg/8 consecutive flat ids
    // (x-major flat -> whole M-bands per XCD -> A-panel L2 reuse). nwg % 8 == 0.
    int gx = gridDim.x;
    int flat = blockIdx.y * gx + blockIdx.x;
    int q8 = (gx * gridDim.y) >> 3;
    int nf = (flat & 7) * q8 + (flat >> 3);
    int m0 = (nf / gx) * 128, n0 = (nf % gx) * 128;

    int srow = l >> 2;
    int scol = (l & 3) * 8;

    f32x4 acc[4][4];
    #pragma unroll
    for (int mi = 0; mi < 4; mi++)
        #pragma unroll
        for (int ni = 0; ni < 4; ni++)
            #pragma unroll
            for (int c = 0; c < 4; c++) acc[mi][ni][c] = 0.f;

    for (int k0 = 0; k0 < K; k0 += 32) {
        __syncthreads();
        #pragma unroll
        for (int p = 0; p < 2; p++) {
            gload16(&A [(size_t)(m0 + w*32 + p*16 + srow)*K + k0 + scol], &Asm[(w*32 + p*16)*32]);
            gload16(&Bt[(size_t)(n0 + w*32 + p*16 + srow)*K + k0 + scol], &Bsm[(w*32 + p*16)*32]);
        }
        __syncthreads();
        short8 af[4], bfr[4];
        #pragma unroll
        for (int mi = 0; mi < 4; mi++)
            af[mi] = *(short8*)&Asm[(wr*64 + mi*16 + lrow)*32 + lhi*8];
        #pragma unroll
        for (int ni = 0; ni < 4; ni++)
            bfr[ni] = *(short8*)&Bsm[(wc*64 + ni*16 + lrow)*32 + lhi*8];
        __builtin_amdgcn_s_setprio(1);
        #pragma unroll
        for (int mi = 0; mi < 4; mi++)
            #pragma unroll
            for (int ni = 0; ni < 4; ni++)
                acc[mi][ni] = __builtin_amdgcn_mfma_f32_16x16x32_bf16(af[mi], bfr[ni], acc[mi][ni], 0, 0, 0);
        __builtin_amdgcn_s_setprio(0);
    }

    #pragma unroll
    for (int mi = 0; mi < 4; mi++)
        #pragma unroll
        for (int ni = 0; ni < 4; ni++) {
            int col = n0 + wc*64 + ni*16 + lrow;
            #pragma unroll
            for (int c = 0; c < 4; c++) {
                int row = m0 + wr*64 + mi*16 + lhi*4 + c;
                if (OUT_MODE == 0) {
                    float v = acc[mi][ni][c] + b0[col];
                    ((float*)Cout)[(size_t)row * N + col] = v;
                } else {
                    int which = col >> 10, hc = col & 1023;
                    const float* bp = (which == 0) ? b0 : (which == 1) ? b1 : b2;
                    float v = acc[mi][ni][c] + bp[hc];
                    if (which == 0) v *= 0.18033688011112042f;  // 0.125 * log2(e)
                    int h = hc >> 6, d = hc & 63;
                    int b = row >> 11, s = row & 2047;
                    ((ushort_t*)Cout)[(size_t)which*PER_BUF + ((size_t)((b*NHEAD + h)*SSEQ) + s)*HDIM + d] = f2bf(v);
                }
            }
        }
}

// ---------------- flash attention v2: swapped QK^T, 32x32 MFMA ----------------
// q: [B,H,S,D] bf16 pre-scaled by 0.125*log2e; k: [B,H,S,D]; vt: [B,H,D,S]; o: [B,S,E] bf16
#define MFMA32(a,b,c) __builtin_amdgcn_mfma_f32_32x32x16_bf16(a, b, c, 0, 0, 0)

__global__ __launch_bounds__(256, 2) void flash_attn2_kernel(
    const ushort_t* __restrict__ q,
    const ushort_t* __restrict__ k,
    const ushort_t* __restrict__ vt,
    ushort_t* __restrict__ o)
{
    __shared__ __attribute__((aligned(16))) ushort_t Ks[2][64*64];  // [kv][d] swizzled
    __shared__ __attribute__((aligned(16))) ushort_t Vs[2][64*64];  // [d][kv] swizzled

    int t = threadIdx.x, w = t >> 6, l = t & 63;
    int l31 = l & 31, hi = l >> 5;

    // XCD-bijective swizzle: 512 wgs, 64/XCD -> 4 whole heads per XCD L2
    int flat = blockIdx.x;
    int wg = (flat & 7) * 64 + (flat >> 3);
    int bh = wg >> 4;
    int q0 = (wg & 15) * 128;

    const ushort_t* qp = q  + (size_t)bh * SSEQ * HDIM;
    const ushort_t* kp = k  + (size_t)bh * SSEQ * HDIM;
    const ushort_t* vp = vt + (size_t)bh * HDIM * SSEQ;

    int lr = l >> 3, lc = l & 7;
    int colel = 8 * (lc ^ lr);   // pre-swizzled global column for staging

    // Q fragments (B-operand): lane holds Q[q0 + w*32 + l31][st*16 + hi*8 + j]
    short8 qf[4];
    int qrow = q0 + w*32 + l31;
    #pragma unroll
    for (int st = 0; st < 4; st++)
        qf[st] = *(const short8*)&qp[(size_t)qrow*HDIM + st*16 + hi*8];

    f32x16 o0 = {}, o1 = {};
    float m_run = -1e30f, l_run = 0.f;

    // stage K rows and Vt rows [w*16, w*16+16) of the 64x64 tiles
    #define STAGE(buf, kv0) { \
        _Pragma("unroll") \
        for (int c = 0; c < 2; c++) { \
            int row = w*16 + c*8 + lr; \
            gload16(&kp[(size_t)(kv0 + row)*HDIM + colel], &Ks[buf][(w*16 + c*8)*64]); \
            gload16(&vp[(size_t)row*SSEQ + (kv0) + colel], &Vs[buf][(w*16 + c*8)*64]); \
        } }

    STAGE(0, 0)
    asm volatile("s_waitcnt vmcnt(0)");
    __syncthreads();
    int cur = 0;

    for (int kv0 = 0; kv0 < SSEQ; kv0 += 64) {
        if (kv0 + 64 < SSEQ) { STAGE(cur ^ 1, kv0 + 64) }

        // ---- S^T = K @ Q^T : lane holds S[q=l31][kv=crow(r,hi)+32*kt]
        f32x16 s0 = {}, s1 = {};
        __builtin_amdgcn_s_setprio(1);
        #pragma unroll
        for (int st = 0; st < 4; st++) {
            int colb = st*16 + hi*8;
            short8 kf0 = *(const short8*)&Ks[cur][l31*64        + (colb ^ ((l31 & 7) << 3))];
            short8 kf1 = *(const short8*)&Ks[cur][(32 + l31)*64 + (colb ^ ((l31 & 7) << 3))];
            s0 = MFMA32(kf0, qf[st], s0);
            s1 = MFMA32(kf1, qf[st], s1);
        }
        __builtin_amdgcn_s_setprio(0);

        // ---- online softmax (log2 domain), per-lane rows; max3-friendly tree
        float ma = fmaxf(s0[0], s0[1]);
        float mb = fmaxf(s0[2], s0[3]);
        float mc = fmaxf(s0[4], s0[5]);
        float md = fmaxf(s0[6], s0[7]);
        ma = fmaxf(fmaxf(ma, s0[8]),  s0[9]);
        mb = fmaxf(fmaxf(mb, s0[10]), s0[11]);
        mc = fmaxf(fmaxf(mc, s0[12]), s0[13]);
        md = fmaxf(fmaxf(md, s0[14]), s0[15]);
        ma = fmaxf(fmaxf(ma, s1[0]),  s1[1]);
        mb = fmaxf(fmaxf(mb, s1[2]),  s1[3]);
        mc = fmaxf(fmaxf(mc, s1[4]),  s1[5]);
        md = fmaxf(fmaxf(md, s1[6]),  s1[7]);
        ma = fmaxf(fmaxf(ma, s1[8]),  s1[9]);
        mb = fmaxf(fmaxf(mb, s1[10]), s1[11]);
        mc = fmaxf(fmaxf(mc, s1[12]), s1[13]);
        md = fmaxf(fmaxf(md, s1[14]), s1[15]);
        float mx = fmaxf(fmaxf(ma, mb), fmaxf(mc, md));
        mx = fmaxf(mx, __shfl_xor(mx, 32));

        if (__any(mx > m_run + 8.f)) {       // defer-max (T13)
            float mnew = fmaxf(m_run, mx);
            float alpha = __builtin_amdgcn_exp2f(m_run - mnew);
            #pragma unroll
            for (int r = 0; r < 16; r++) { o0[r] *= alpha; o1[r] *= alpha; }
            l_run *= alpha;
            m_run = mnew;
        }
        float r0 = 0.f, r1 = 0.f, r2 = 0.f, r3 = 0.f;
        #pragma unroll
        for (int r = 0; r < 16; r += 4) {
            s0[r]   = __builtin_amdgcn_exp2f(s0[r]   - m_run); r0 += s0[r];
            s0[r+1] = __builtin_amdgcn_exp2f(s0[r+1] - m_run); r1 += s0[r+1];
            s0[r+2] = __builtin_amdgcn_exp2f(s0[r+2] - m_run); r2 += s0[r+2];
            s0[r+3] = __builtin_amdgcn_exp2f(s0[r+3] - m_run); r3 += s0[r+3];
        }
        #pragma unroll
        for (int r = 0; r < 16; r += 4) {
            s1[r]   = __builtin_amdgcn_exp2f(s1[r]   - m_run); r0 += s1[r];
            s1[r+1] = __builtin_amdgcn_exp2f(s1[r+1] - m_run); r1 += s1[r+1];
            s1[r+2] = __builtin_amdgcn_exp2f(s1[r+2] - m_run); r2 += s1[r+2];
            s1[r+3] = __builtin_amdgcn_exp2f(s1[r+3] - m_run); r3 += s1[r+3];
        }
        float rs = (r0 + r1) + (r2 + r3);
        rs += __shfl_xor(rs, 32);
        l_run += rs;

        // ---- P -> bf16 B-fragments via v_cvt_pk_bf16_f32 + permlane32_swap (T12)
        // pfr[ks][j] = P[q=l31][kv = 16*ks + 8*hi + j]
        // swap(a,b): .x = {lo:a_lo, hi:b_lo}, .y = {lo:a_hi, hi:b_hi}
        short8 pfr[4];
        #pragma unroll
        for (int kt = 0; kt < 2; kt++) {
            #pragma unroll
            for (int sub = 0; sub < 2; sub++) {
                const f32x16& sv = (kt == 0) ? s0 : s1;
                int b8 = sub * 8;
                unsigned a0 = cvt_pk_bf16(sv[b8+0], sv[b8+1]);
                unsigned a1 = cvt_pk_bf16(sv[b8+2], sv[b8+3]);
                unsigned b0 = cvt_pk_bf16(sv[b8+4], sv[b8+5]);
                unsigned b1 = cvt_pk_bf16(sv[b8+6], sv[b8+7]);
                uint2v rr0 = __builtin_amdgcn_permlane32_swap(a0, b0, false, false);
                uint2v rr1 = __builtin_amdgcn_permlane32_swap(a1, b1, false, false);
                union { unsigned u[4]; short8 v; } pf;
                pf.u[0] = rr0.x; pf.u[1] = rr1.x; pf.u[2] = rr0.y; pf.u[3] = rr1.y;
                pfr[kt*2 + sub] = pf.v;
            }
        }

        // ---- O^T += V^T P^T : lane holds O[q=l31][d=crow(r,hi)+32*dt]
        __builtin_amdgcn_s_setprio(1);
        #pragma unroll
        for (int ks = 0; ks < 4; ks++) {
            int colb = ks*16 + hi*8;
            short8 vf0 = *(const short8*)&Vs[cur][l31*64        + (colb ^ ((l31 & 7) << 3))];
            short8 vf1 = *(const short8*)&Vs[cur][(32 + l31)*64 + (colb ^ ((l31 & 7) << 3))];
            o0 = MFMA32(vf0, pfr[ks], o0);
            o1 = MFMA32(vf1, pfr[ks], o1);
        }
        __builtin_amdgcn_s_setprio(0);

        asm volatile("s_waitcnt vmcnt(0)");
        __syncthreads();
        cur ^= 1;
    }

    // ---- epilogue: normalize, LDS roundtrip for coalesced stores
    float rl = 1.f / l_run;
    ushort_t* Ot = ((ushort_t*)Ks) + w*(32*64);   // per-wave 4KB
    #pragma unroll
    for (int dt = 0; dt < 2; dt++)
        #pragma unroll
        for (int rq = 0; rq < 4; rq++) {
            float v0 = (dt ? o1[rq*4+0] : o0[rq*4+0]) * rl;
            float v1 = (dt ? o1[rq*4+1] : o0[rq*4+1]) * rl;
            float v2 = (dt ? o1[rq*4+2] : o0[rq*4+2]) * rl;
            float v3 = (dt ? o1[rq*4+3] : o0[rq*4+3]) * rl;
            int d0 = dt*32 + rq*8 + hi*4;
            uint2v pw = { cvt_pk_bf16(v0, v1), cvt_pk_bf16(v2, v3) };
            *(uint2v*)&Ot[l31*64 + (d0 ^ ((l31 & 7) << 3))] = pw;
        }

    int b = bh >> 4, h = bh & 15;
    int q2 = l >> 1, dh = (l & 1) * 32;
    size_t obase = ((size_t)(b*SSEQ) + q0 + w*32 + q2)*EMBED + h*HDIM;
    #pragma unroll
    for (int j = 0; j < 4; j++) {
        int d = dh + j*8;
        short8 ov = *(short8*)&Ot[q2*64 + (d ^ ((q2 & 7) << 3))];
        *(short8*)&o[obase + d] = ov;
    }
}

extern "C" void kernel_launch(void* const* d_in, const int* in_sizes, int n_in,
                              void* d_out, int out_size, void* d_ws, size_t ws_size,
                              hipStream_t stream) {
    const float* x  = (const float*)d_in[0];
    const float* Wq = (const float*)d_in[1];
    const float* bq = (const float*)d_in[2];
    const float* Wk = (const float*)d_in[3];
    const float* bk = (const float*)d_in[4];
    const float* Wv = (const float*)d_in[5];
    const float* bv = (const float*)d_in[6];
    const float* Wo = (const float*)d_in[7];
    const float* bo = (const float*)d_in[8];

    char* ws = (char*)d_ws;
    ushort_t* xb  = (ushort_t*)(ws);                    // 0-8 MB: x bf16, later reused as attn-out
    ushort_t* WqT = (ushort_t*)(ws + (8u  << 20));      // WqT|WkT|WvT contiguous [3072][1024]
    ushort_t* WkT = (ushort_t*)(ws + (10u << 20));
    ushort_t* WvT = (ushort_t*)(ws + (12u << 20));
    ushort_t* WoT = (ushort_t*)(ws + (14u << 20));
    ushort_t* qb  = (ushort_t*)(ws + (16u << 20));      // q|k|v contiguous, 8 MB each
    ushort_t* kb  = (ushort_t*)(ws + (24u << 20));
    ushort_t* vb  = (ushort_t*)(ws + (32u << 20));
    ushort_t* vtb = (ushort_t*)(ws + (40u << 20));      // V transposed [B,H,D,S]
    ushort_t* ab  = xb;

    int nx = MROWS * EMBED;
    cast_bf16_kernel<<<nx/(256*4), 256, 0, stream>>>(x, xb, nx);

    transpose_cast4_kernel<<<dim3(EMBED/32, EMBED/32, 4), dim3(32, 8), 0, stream>>>(
        Wq, Wk, Wv, Wo, WqT, WkT, WvT, WoT);

    gemm_bt_kernel<2><<<dim3(QKV_N/128, MROWS/128), 256, 0, stream>>>(
        xb, WqT, bq, bk, bv, qb, MROWS, QKV_N, EMBED);

    transpose_v_kernel<<<dim3(SSEQ/64, BB*NHEAD), 256, 0, stream>>>(vb, vtb);

    flash_attn2_kernel<<<512, 256, 0, stream>>>(qb, kb, vtb, ab);

    gemm_bt_kernel<0><<<dim3(EMBED/128, MROWS/128), 256, 0, stream>>>(
        ab, WoT, bo, bo, bo, d_out, MROWS, EMBED, EMBED);
}